// Round 2
// 628.159 us; speedup vs baseline: 1.2781x; 1.2781x over previous
//
#include <hip/hip_runtime.h>

// ---------------------------------------------------------------------------
// GAT 2-layer GNN on MI355X. fp32 throughout.
// Pipeline:
//   memset(rcnt) -> k_bin (256-node-range counting-sort level 1)
//   -> k_scanR (range prefix) -> k_sort (per-range LDS counting sort:
//      deg + row_ptr + ssrc scatter, NO scattered global atomics)
//   -> gemm1(K-split, reg-prefetch) -> k_post
//   -> agg1(batched-gather softmax) -> gemm2(+e epilogue) -> agg2
//   -> pool+final linear
// R7 change (scattered-atomic elimination):
//   R6 profile: k_bin 143us with WRITE_SIZE=126MB (payload only 26MB) --
//   the 3.3M scattered device-scope deg atomics write through memory-side
//   at ~32B each (~100MB), capping the kernel at ~1TB/s. k_scat2 had the
//   same pathology via 3.3M returning cursor atomics. New design is a
//   2-level counting sort: level 1 bins into 391 ranges of 256 dst nodes
//   (LDS counters + ~150K reservation atomics on 1.5KB); level 2 builds
//   the per-node histogram, scan, row_ptr, and ssrc scatter with LDS
//   atomics only, one block per range. deg/cursor/k_scan1-3/k_scat2 gone.
// R7b: previous submission hit a container-level failure; only suspect in
//   the kernel was peak-workspace growth (stg pushed it ~1MB past the R6
//   high-water mark). stg now ALIASES h1+hpart (38.4MB >= 32.8MB needed):
//   stg is dead after k_sort, which completes (stream order) before
//   k_gemm1/k_post first write hpart/h1. Peak ws ~77.6MB.
// ---------------------------------------------------------------------------

#define LRELU(v) ((v) >= 0.f ? (v) : 0.2f * (v))

// Level 1: bin edges into 256-node dst ranges. Block = 8192 edges
// (256 thr x 32), two passes over the edge slice (2nd read L2-hits).
__global__ __launch_bounds__(256) void k_bin(const int* __restrict__ ei,
                                             int2* __restrict__ stg,
                                             int* __restrict__ rcnt,
                                             int E0, int Etot, int nr, int cap) {
    __shared__ int cnt[1024];
    __shared__ int base[1024];
    const int t = threadIdx.x;
    for (int i = t; i < nr; i += 256) cnt[i] = 0;
    __syncthreads();
    const int e0 = blockIdx.x * 8192;
    // pass 1: count dst ranges (dst-only load)
#pragma unroll 4
    for (int k = 0; k < 32; k++) {
        int e = e0 + k * 256 + t;
        if (e < Etot) {
            int d = (e < E0) ? ei[E0 + e] : (e - E0);
            atomicAdd(&cnt[d >> 8], 1);
        }
    }
    __syncthreads();
    // reserve per-range staging segments; reuse cnt[] as local cursor
    for (int i = t; i < nr; i += 256) {
        int c = cnt[i];
        base[i] = c ? atomicAdd(&rcnt[i], c) : 0;
        cnt[i] = 0;
    }
    __syncthreads();
    // pass 2: scatter (s,d) compactly into this block's per-range runs
#pragma unroll 4
    for (int k = 0; k < 32; k++) {
        int e = e0 + k * 256 + t;
        if (e < Etot) {
            int s, d;
            if (e < E0) {
                s = ei[e];
                d = ei[E0 + e];
            } else {
                s = d = e - E0;
            }
            int r = d >> 8;
            int slot = base[r] + atomicAdd(&cnt[r], 1);
            stg[(size_t)r * cap + slot] = make_int2(s, d);
        }
    }
}

// Exclusive prefix over range counts (nr <= 1024) + row_ptr[N] terminator.
__global__ __launch_bounds__(1024) void k_scanR(const int* __restrict__ rcnt,
                                                int* __restrict__ rbase,
                                                int* __restrict__ row_ptr,
                                                int nr, int N, int Etot) {
    __shared__ int sd[1024];
    int t = threadIdx.x;
    int v = (t < nr) ? rcnt[t] : 0;
    sd[t] = v;
    __syncthreads();
    for (int off = 1; off < 1024; off <<= 1) {
        int o = (t >= off) ? sd[t - off] : 0;
        __syncthreads();
        sd[t] += o;
        __syncthreads();
    }
    if (t < nr) rbase[t] = sd[t] - v;
    if (t == 0) row_ptr[N] = Etot;
}

// Level 2: one block per 256-node range. LDS histogram -> exclusive scan
// -> row_ptr -> LDS-cursor scatter into the range's contiguous CSR window.
// No global atomics anywhere.
__global__ __launch_bounds__(512) void k_sort(const int2* __restrict__ stg,
                                              const int* __restrict__ rcnt,
                                              const int* __restrict__ rbase,
                                              int* __restrict__ row_ptr,
                                              int* __restrict__ ssrc,
                                              int N, int cap) {
    __shared__ int hist[256];
    __shared__ int hs[256];
    const int r = blockIdx.x;
    const int t = threadIdx.x;
    const int n0 = r << 8;
    const int cnt = rcnt[r];
    const int rb = rbase[r];
    const int2* seg = stg + (size_t)r * cap;
    if (t < 256) hist[t] = 0;
    __syncthreads();
    for (int i = t; i < cnt; i += 512) {
        int d = seg[i].y;
        atomicAdd(&hist[d - n0], 1);
    }
    __syncthreads();
    if (t < 256) hs[t] = hist[t];
    __syncthreads();
    for (int off = 1; off < 256; off <<= 1) {
        int o = (t < 256 && t >= off) ? hs[t - off] : 0;
        __syncthreads();
        if (t < 256) hs[t] += o;
        __syncthreads();
    }
    if (t < 256) {
        int excl = hs[t] - hist[t];
        int node = n0 + t;
        if (node < N) row_ptr[node] = rb + excl;
        hist[t] = excl; // reuse as running cursor
    }
    __syncthreads();
    for (int i = t; i < cnt; i += 512) {
        int2 sd2 = seg[i];
        int off = atomicAdd(&hist[sd2.y - n0], 1);
        ssrc[rb + off] = sd2.x;
    }
}

// GEMM1 (K-split): block b -> row tile (b>>1)*256, K half (b&1)*256.
// Register double-buffer: next chunk global->regs issued before compute.
__global__ __launch_bounds__(256) void k_gemm1(const float* __restrict__ x,
                                               const float* __restrict__ W,
                                               float* __restrict__ hpart, int N) {
    __shared__ float xs[32 * 260]; // [k][row]
    __shared__ float ws[32 * 36];  // [k][c]
    const int t = threadIdx.x;
    const int g = t >> 2, cg = t & 3;
    const int row0 = (blockIdx.x >> 1) * 256;
    const int koff = (blockIdx.x & 1) * 256;

    float acc[4][8];
#pragma unroll
    for (int i = 0; i < 4; i++)
#pragma unroll
        for (int j = 0; j < 8; j++) acc[i][j] = 0.f;

    float4 xr[8];
    float4 wr;
    const int xrow = t >> 3, xc4 = t & 7;
    const int wk = t >> 3, wc4 = t & 7;

    auto load_chunk = [&](int kc) {
#pragma unroll
        for (int ii = 0; ii < 8; ii++) {
            int row = xrow + ii * 32;
            int rr = row0 + row;
            if (rr >= N) rr = N - 1; // clamp (harmless duplicate reads)
            xr[ii] = *(const float4*)&x[(size_t)rr * 512 + kc + xc4 * 4];
        }
        wr = *(const float4*)&W[(size_t)(kc + wk) * 32 + wc4 * 4];
    };

    load_chunk(koff);
    for (int c = 0; c < 8; c++) {
        __syncthreads();
#pragma unroll
        for (int ii = 0; ii < 8; ii++) {
            int row = xrow + ii * 32;
            xs[(xc4 * 4 + 0) * 260 + row] = xr[ii].x;
            xs[(xc4 * 4 + 1) * 260 + row] = xr[ii].y;
            xs[(xc4 * 4 + 2) * 260 + row] = xr[ii].z;
            xs[(xc4 * 4 + 3) * 260 + row] = xr[ii].w;
        }
        ws[wk * 36 + wc4 * 4 + 0] = wr.x;
        ws[wk * 36 + wc4 * 4 + 1] = wr.y;
        ws[wk * 36 + wc4 * 4 + 2] = wr.z;
        ws[wk * 36 + wc4 * 4 + 3] = wr.w;
        __syncthreads();
        if (c < 7) load_chunk(koff + (c + 1) * 32); // prefetch next chunk
#pragma unroll 8
        for (int k = 0; k < 32; k++) {
            float4 xv = *(const float4*)&xs[k * 260 + g * 4];
            float4 w0 = *(const float4*)&ws[k * 36 + cg * 8];
            float4 w1 = *(const float4*)&ws[k * 36 + cg * 8 + 4];
            const float xr4[4] = {xv.x, xv.y, xv.z, xv.w};
#pragma unroll
            for (int i = 0; i < 4; i++) {
                acc[i][0] += xr4[i] * w0.x;
                acc[i][1] += xr4[i] * w0.y;
                acc[i][2] += xr4[i] * w0.z;
                acc[i][3] += xr4[i] * w0.w;
                acc[i][4] += xr4[i] * w1.x;
                acc[i][5] += xr4[i] * w1.y;
                acc[i][6] += xr4[i] * w1.z;
                acc[i][7] += xr4[i] * w1.w;
            }
        }
    }

    float* hp = hpart + (size_t)(blockIdx.x & 1) * N * 32;
#pragma unroll
    for (int i = 0; i < 4; i++) {
        int r = row0 + g * 4 + i;
        if (r < N) {
            *(float4*)&hp[(size_t)r * 32 + cg * 8] =
                make_float4(acc[i][0], acc[i][1], acc[i][2], acc[i][3]);
            *(float4*)&hp[(size_t)r * 32 + cg * 8 + 4] =
                make_float4(acc[i][4], acc[i][5], acc[i][6], acc[i][7]);
        }
    }
}

// Sum the two K-half partials, write h, and compute es/ed.
__global__ __launch_bounds__(256) void k_post(const float* __restrict__ hpart,
                                              const float* __restrict__ a_src,
                                              const float* __restrict__ a_dst,
                                              float* __restrict__ h,
                                              float* __restrict__ es,
                                              float* __restrict__ ed, int N) {
    int i = blockIdx.x * 256 + threadIdx.x;
    if (i >= N * 4) return;
    int head = i & 3;
    const float* ha = hpart;
    const float* hb = hpart + (size_t)N * 32;
    float4 a0 = *(const float4*)&ha[(size_t)i * 8];
    float4 a1 = *(const float4*)&ha[(size_t)i * 8 + 4];
    float4 b0 = *(const float4*)&hb[(size_t)i * 8];
    float4 b1 = *(const float4*)&hb[(size_t)i * 8 + 4];
    float4 h0 = make_float4(a0.x + b0.x, a0.y + b0.y, a0.z + b0.z, a0.w + b0.w);
    float4 h1 = make_float4(a1.x + b1.x, a1.y + b1.y, a1.z + b1.z, a1.w + b1.w);
    *(float4*)&h[(size_t)i * 8] = h0;
    *(float4*)&h[(size_t)i * 8 + 4] = h1;
    const float* as = &a_src[head * 8];
    const float* ad = &a_dst[head * 8];
    float s1 = h0.x * as[0] + h0.y * as[1] + h0.z * as[2] + h0.w * as[3] +
               h1.x * as[4] + h1.y * as[5] + h1.z * as[6] + h1.w * as[7];
    float s2 = h0.x * ad[0] + h0.y * ad[1] + h0.z * ad[2] + h0.w * ad[3] +
               h1.x * ad[4] + h1.y * ad[5] + h1.z * ad[6] + h1.w * ad[7];
    es[i] = s1;
    ed[i] = s2;
}

// Single-pass aggregation, direct exp. One wave per dst, 4 dst/block.
// 8-deep gather batching; predicated tail keeps full pipeline depth.
template <int HC>
__global__ __launch_bounds__(256) void k_agg(const int* __restrict__ row_ptr,
                                             const int* __restrict__ ssrc,
                                             const float* __restrict__ hsrc,
                                             const float* __restrict__ es,
                                             const float* __restrict__ ed,
                                             const float* __restrict__ bias,
                                             float* __restrict__ out, int N) {
    constexpr int E2 = 64 / HC;
    constexpr int U = 8;
    const int lane = threadIdx.x & 63;
    const int d = blockIdx.x * 4 + (threadIdx.x >> 6);
    if (d >= N) return;
    const int c = lane & (HC - 1);
    const int e2 = lane / HC;
    const int hh = c / (HC / 4);
    const int start = row_ptr[d];
    const int deg = row_ptr[d + 1] - start;
    const float edh = ed[d * 4 + hh];
    const int j0 = (e2 < deg) ? e2 : 0;

    float l = 0.f, acc = 0.f;
    for (int jb = e2; jb < deg; jb += U * E2) {
        int sv[U];
        float wv[U];
#pragma unroll
        for (int u = 0; u < U; u++) {
            int jj = jb + u * E2;
            bool ok = jj < deg;
            wv[u] = ok ? 1.f : 0.f;
            sv[u] = ssrc[start + (ok ? jj : j0)];
        }
        float hv[U];
#pragma unroll
        for (int u = 0; u < U; u++) hv[u] = hsrc[(size_t)sv[u] * HC + c];
        float pv[U];
#pragma unroll
        for (int u = 0; u < U; u++) {
            float ev = es[sv[u] * 4 + hh] + edh;
            ev = LRELU(ev);
            pv[u] = __expf(ev) * wv[u];
        }
#pragma unroll
        for (int u = 0; u < U; u++) {
            l += pv[u];
            acc += pv[u] * hv[u];
        }
    }
#pragma unroll
    for (int off = HC; off < 64; off <<= 1) {
        l += __shfl_xor(l, off);
        acc += __shfl_xor(acc, off);
    }
    if (lane < HC) {
        float v = acc / (l + 1e-16f) + bias[c];
        out[(size_t)d * HC + c] = v > 0.f ? v : 0.f;
    }
}

// GEMM2: [N,32] @ [32,16] -> h2[N,16] + e_src2/e_dst2 epilogue.
__global__ __launch_bounds__(256) void k_gemm2(const float* __restrict__ g1,
                                               const float* __restrict__ W2,
                                               const float* __restrict__ a2s,
                                               const float* __restrict__ a2d,
                                               float* __restrict__ h2,
                                               float* __restrict__ es2,
                                               float* __restrict__ ed2, int N) {
    __shared__ float rows[64 * 33];
    __shared__ float ws[32 * 20];
    int t = threadIdx.x;
    int n0 = blockIdx.x * 64;
#pragma unroll
    for (int ii = 0; ii < 2; ii++) {
        int idx = ii * 256 + t;
        int node = idx >> 3, c4 = idx & 7;
        float4 v = make_float4(0.f, 0.f, 0.f, 0.f);
        if (n0 + node < N) v = *(const float4*)&g1[(size_t)(n0 + node) * 32 + c4 * 4];
        rows[node * 33 + c4 * 4 + 0] = v.x;
        rows[node * 33 + c4 * 4 + 1] = v.y;
        rows[node * 33 + c4 * 4 + 2] = v.z;
        rows[node * 33 + c4 * 4 + 3] = v.w;
    }
    if (t < 128) {
        int r = t >> 2, c4 = t & 3;
        float4 v = *(const float4*)&W2[r * 16 + c4 * 4];
        ws[r * 20 + c4 * 4 + 0] = v.x;
        ws[r * 20 + c4 * 4 + 1] = v.y;
        ws[r * 20 + c4 * 4 + 2] = v.z;
        ws[r * 20 + c4 * 4 + 3] = v.w;
    }
    __syncthreads();
    int node = t >> 2, q = t & 3;
    int n = n0 + node;
    if (n >= N) return;
    float acc[4] = {0.f, 0.f, 0.f, 0.f};
#pragma unroll 8
    for (int cc = 0; cc < 32; cc++) {
        float v = rows[node * 33 + cc];
        float4 w = *(const float4*)&ws[cc * 20 + q * 4];
        acc[0] += v * w.x;
        acc[1] += v * w.y;
        acc[2] += v * w.z;
        acc[3] += v * w.w;
    }
    *(float4*)&h2[(size_t)n * 16 + q * 4] = make_float4(acc[0], acc[1], acc[2], acc[3]);
    float s1 = 0.f, s2 = 0.f;
#pragma unroll
    for (int j = 0; j < 4; j++) {
        s1 += acc[j] * a2s[q * 4 + j];
        s2 += acc[j] * a2d[q * 4 + j];
    }
    es2[n * 4 + q] = s1;
    ed2[n * 4 + q] = s2;
}

// Pool (mean over sorted batch) + final linear. One block per graph.
__global__ __launch_bounds__(256) void k_final(const float* __restrict__ h3,
                                               const int* __restrict__ batch,
                                               const float* __restrict__ Wf,
                                               const float* __restrict__ bf,
                                               float* __restrict__ out, int N) {
    __shared__ float part[16][17];
    __shared__ float pooled[16];
    int g = blockIdx.x;
    int t = threadIdx.x;

    int lo = 0, b = N;
    while (lo < b) { int mid = (lo + b) >> 1; if (batch[mid] < g) lo = mid + 1; else b = mid; }
    int hi = lo; b = N;
    while (hi < b) { int mid = (hi + b) >> 1; if (batch[mid] < g + 1) hi = mid + 1; else b = mid; }

    int ch = t & 15, r = t >> 4;
    float acc = 0.f;
    for (int i = lo + r; i < hi; i += 16) acc += h3[(size_t)i * 16 + ch];
    part[r][ch] = acc;
    __syncthreads();
    if (t < 16) {
        float s = 0.f;
#pragma unroll
        for (int rr = 0; rr < 16; rr++) s += part[rr][t];
        float cnt = (float)(hi - lo);
        pooled[t] = s / fmaxf(cnt, 1.f);
    }
    __syncthreads();
    if (t < 10) {
        float v = bf[t];
#pragma unroll
        for (int cc = 0; cc < 16; cc++) v += pooled[cc] * Wf[cc * 10 + t];
        out[g * 10 + t] = v;
    }
}

extern "C" void kernel_launch(void* const* d_in, const int* in_sizes, int n_in,
                              void* d_out, int out_size, void* d_ws, size_t ws_size,
                              hipStream_t stream) {
    const float* x   = (const float*)d_in[0];
    const int*   ei  = (const int*)d_in[1];
    const int*   bat = (const int*)d_in[2];
    const float* W1  = (const float*)d_in[3];
    const float* as1 = (const float*)d_in[4];
    const float* ad1 = (const float*)d_in[5];
    const float* b1  = (const float*)d_in[6];
    const float* W2  = (const float*)d_in[7];
    const float* as2 = (const float*)d_in[8];
    const float* ad2 = (const float*)d_in[9];
    const float* b2  = (const float*)d_in[10];
    const float* Wf  = (const float*)d_in[11];
    const float* bf  = (const float*)d_in[12];
    float* outp = (float*)d_out;

    const int N = in_sizes[2];
    const int E0 = in_sizes[1] / 2;
    const int Etot = E0 + N;
    const int nr = (N + 255) >> 8;        // 256-node dst ranges (<=1024)
    const int cap = Etot / nr + 2048;     // per-range staging cap (~20 sigma)

    char* w = (char*)d_ws;
    auto alloc = [&](size_t bytes) -> char* {
        char* p = w;
        w += (bytes + 255) & ~(size_t)255;
        return p;
    };
    float* h1    = (float*)alloc((size_t)N * 32 * 4);
    float* hpart = (float*)alloc((size_t)2 * N * 32 * 4);
    float* es1 = (float*)alloc((size_t)N * 4 * 4);
    float* ed1 = (float*)alloc((size_t)N * 4 * 4);
    float* g1  = (float*)alloc((size_t)N * 32 * 4);
    float* h2  = (float*)alloc((size_t)N * 16 * 4);
    float* es2 = (float*)alloc((size_t)N * 4 * 4);
    float* ed2 = (float*)alloc((size_t)N * 4 * 4);
    int* rcnt    = (int*)alloc(4096);
    int* rbase   = (int*)alloc(4096);
    int* row_ptr = (int*)alloc((size_t)(N + 1) * 4);
    int* ssrc    = (int*)alloc((size_t)Etot * 4);
    // stg ALIASES h1+hpart (38.4MB window, stg needs nr*cap*8 ~= 32.8MB).
    // Safe by stream order: stg dead after k_sort; hpart first written by
    // k_gemm1, h1 by k_post, both launched after k_sort.
    int2* stg = (int2*)h1;
    float* h3 = h1; // h1 dead after agg1; reuse for layer-2 output

    const int nbN = (N + 255) / 256;

    hipMemsetAsync(rcnt, 0, 4096, stream);
    k_bin<<<(Etot + 8191) / 8192, 256, 0, stream>>>(ei, stg, rcnt, E0, Etot, nr, cap);
    k_scanR<<<1, 1024, 0, stream>>>(rcnt, rbase, row_ptr, nr, N, Etot);
    k_sort<<<nr, 512, 0, stream>>>(stg, rcnt, rbase, row_ptr, ssrc, N, cap);
    k_gemm1<<<2 * nbN, 256, 0, stream>>>(x, W1, hpart, N);
    k_post<<<(N * 4 + 255) / 256, 256, 0, stream>>>(hpart, as1, ad1, h1, es1, ed1, N);
    k_agg<32><<<(N + 3) / 4, 256, 0, stream>>>(row_ptr, ssrc, h1, es1, ed1, b1, g1, N);
    k_gemm2<<<(N + 63) / 64, 256, 0, stream>>>(g1, W2, as2, ad2, h2, es2, ed2, N);
    k_agg<16><<<(N + 3) / 4, 256, 0, stream>>>(row_ptr, ssrc, h2, es2, ed2, b2, h3, N);
    k_final<<<64, 256, 0, stream>>>(h3, bat, Wf, bf, outp, N);
}

// Round 3
// 627.488 us; speedup vs baseline: 1.2795x; 1.0011x over previous
//
#include <hip/hip_runtime.h>

// ---------------------------------------------------------------------------
// GAT 2-layer GNN on MI355X. fp32 throughout.
// Pipeline (7 dispatches):
//   memset(rcnt) -> k_bin (256-node-range counting-sort level 1)
//   -> k_sort (self-computed range base + per-range LDS counting sort:
//      row_ptr + ssrc, NO scattered global atomics)
//   -> k_gemm1 (full-K 128-row tiles; epilogue computes es1/ed1 -> k_post gone)
//   -> k_agg1 (batched-gather softmax; epilogue fuses gemm2 [32x16] + es2/ed2
//      via readlane broadcast -> k_gemm2 and g1 gone)
//   -> k_agg<16> (layer-2 aggregation) -> k_final (pool + linear)
// R8 change (structural fusion):
//   R7 profile: top-5 all harness fillBuffer (~120us, untouchable); our
//   kernels all < 120us. Remaining waste = intermediate round-trips:
//   hpart 51MB (gemm1 K-split partials) and g1 26MB (gemm2 input), plus
//   3 launches (k_post, k_gemm2, k_scanR). All three fused away:
//   * gemm1: 128-row x full-K=512 tiles (782 blocks, same balance as the
//     old 782 K-split blocks); per-thread col-group == one head, so es/ed
//     are thread-local dots in the epilogue.
//   * agg1 epilogue: g1 row sits in lanes 0-31 post-reduce; 32 readlane
//     FMAs against LDS W2 give h2 row + es2/ed2 partials (shfl_xor 4-lane
//     reduce). Single barrier at kernel start (stage W2/b1/a2s/a2d).
//   * k_sort: each block reduces rcnt[0..r) itself (<=391 L2-hot ints).
// ---------------------------------------------------------------------------

#define LRELU(v) ((v) >= 0.f ? (v) : 0.2f * (v))

// Level 1: bin edges into 256-node dst ranges. Block = 8192 edges
// (256 thr x 32), two passes over the edge slice (2nd read L2-hits).
__global__ __launch_bounds__(256) void k_bin(const int* __restrict__ ei,
                                             int2* __restrict__ stg,
                                             int* __restrict__ rcnt,
                                             int E0, int Etot, int nr, int cap) {
    __shared__ int cnt[1024];
    __shared__ int base[1024];
    const int t = threadIdx.x;
    for (int i = t; i < nr; i += 256) cnt[i] = 0;
    __syncthreads();
    const int e0 = blockIdx.x * 8192;
    // pass 1: count dst ranges (dst-only load)
#pragma unroll 4
    for (int k = 0; k < 32; k++) {
        int e = e0 + k * 256 + t;
        if (e < Etot) {
            int d = (e < E0) ? ei[E0 + e] : (e - E0);
            atomicAdd(&cnt[d >> 8], 1);
        }
    }
    __syncthreads();
    // reserve per-range staging segments; reuse cnt[] as local cursor
    for (int i = t; i < nr; i += 256) {
        int c = cnt[i];
        base[i] = c ? atomicAdd(&rcnt[i], c) : 0;
        cnt[i] = 0;
    }
    __syncthreads();
    // pass 2: scatter (s,d) compactly into this block's per-range runs
#pragma unroll 4
    for (int k = 0; k < 32; k++) {
        int e = e0 + k * 256 + t;
        if (e < Etot) {
            int s, d;
            if (e < E0) {
                s = ei[e];
                d = ei[E0 + e];
            } else {
                s = d = e - E0;
            }
            int r = d >> 8;
            int slot = base[r] + atomicAdd(&cnt[r], 1);
            stg[(size_t)r * cap + slot] = make_int2(s, d);
        }
    }
}

// Level 2: one block per 256-node range. Self-computed base (reduction over
// rcnt[0..r)), LDS histogram -> exclusive scan -> row_ptr -> LDS-cursor
// scatter into the range's contiguous CSR window. No global atomics.
__global__ __launch_bounds__(512) void k_sort(const int2* __restrict__ stg,
                                              const int* __restrict__ rcnt,
                                              int* __restrict__ row_ptr,
                                              int* __restrict__ ssrc,
                                              int N, int Etot, int nr, int cap) {
    __shared__ int hist[256];
    __shared__ int hs[256];
    __shared__ int red[512];
    const int r = blockIdx.x;
    const int t = threadIdx.x;
    // rb = sum of rcnt[0..r)
    int part = 0;
    for (int i = t; i < r; i += 512) part += rcnt[i];
    red[t] = part;
    if (t < 256) hist[t] = 0;
    __syncthreads();
    for (int off = 256; off > 0; off >>= 1) {
        if (t < off) red[t] += red[t + off];
        __syncthreads();
    }
    const int rb = red[0];
    const int n0 = r << 8;
    const int cnt = rcnt[r];
    const int2* seg = stg + (size_t)r * cap;
    for (int i = t; i < cnt; i += 512) {
        int d = seg[i].y;
        atomicAdd(&hist[d - n0], 1);
    }
    __syncthreads();
    if (t < 256) hs[t] = hist[t];
    __syncthreads();
    for (int off = 1; off < 256; off <<= 1) {
        int o = (t < 256 && t >= off) ? hs[t - off] : 0;
        __syncthreads();
        if (t < 256) hs[t] += o;
        __syncthreads();
    }
    if (t < 256) {
        int excl = hs[t] - hist[t];
        int node = n0 + t;
        if (node < N) row_ptr[node] = rb + excl;
        hist[t] = excl; // reuse as running cursor
    }
    if (r == nr - 1 && t == 0) row_ptr[N] = Etot;
    __syncthreads();
    for (int i = t; i < cnt; i += 512) {
        int2 sd2 = seg[i];
        int off = atomicAdd(&hist[sd2.y - n0], 1);
        ssrc[rb + off] = sd2.x;
    }
}

// GEMM1: 128-row tiles x full K=512 (16 chunks of 32). Register prefetch of
// next chunk. Epilogue: write h (no relu; layer-1 h is pre-activation) and
// es/ed per (row, head) -- thread col-group cg == head, so the 8-wide dots
// are thread-local. Replaces old K-split gemm1 + k_post (hpart deleted).
__global__ __launch_bounds__(256) void k_gemm1(const float* __restrict__ x,
                                               const float* __restrict__ W,
                                               const float* __restrict__ a_src,
                                               const float* __restrict__ a_dst,
                                               float* __restrict__ h,
                                               float* __restrict__ es,
                                               float* __restrict__ ed, int N) {
    __shared__ float xs[32 * 132]; // [k][row], pad 132 (float2-aligned reads)
    __shared__ float ws[32 * 36];  // [k][c]
    const int t = threadIdx.x;
    const int r0 = (t >> 2) * 2; // 2 rows per thread
    const int cg = t & 3;        // 8-col group == head index
    const int row0 = blockIdx.x * 128;

    float acc[2][8];
#pragma unroll
    for (int i = 0; i < 2; i++)
#pragma unroll
        for (int j = 0; j < 8; j++) acc[i][j] = 0.f;

    float4 xr[4];
    float4 wr;
    const int xrow = t >> 3, xc4 = t & 7; // 128 rows x 8 float4/row = 1024 slots
    const int wk = t >> 3, wc4 = t & 7;   // 32 k x 8 float4 = 256 slots

    auto load_chunk = [&](int kc) {
#pragma unroll
        for (int ii = 0; ii < 4; ii++) {
            int row = xrow + ii * 32;
            int rr = row0 + row;
            if (rr >= N) rr = N - 1; // clamp (harmless duplicate reads)
            xr[ii] = *(const float4*)&x[(size_t)rr * 512 + kc + xc4 * 4];
        }
        wr = *(const float4*)&W[(size_t)(kc + wk) * 32 + wc4 * 4];
    };

    load_chunk(0);
    for (int c = 0; c < 16; c++) {
        __syncthreads();
#pragma unroll
        for (int ii = 0; ii < 4; ii++) {
            int row = xrow + ii * 32;
            xs[(xc4 * 4 + 0) * 132 + row] = xr[ii].x;
            xs[(xc4 * 4 + 1) * 132 + row] = xr[ii].y;
            xs[(xc4 * 4 + 2) * 132 + row] = xr[ii].z;
            xs[(xc4 * 4 + 3) * 132 + row] = xr[ii].w;
        }
        ws[wk * 36 + wc4 * 4 + 0] = wr.x;
        ws[wk * 36 + wc4 * 4 + 1] = wr.y;
        ws[wk * 36 + wc4 * 4 + 2] = wr.z;
        ws[wk * 36 + wc4 * 4 + 3] = wr.w;
        __syncthreads();
        if (c < 15) load_chunk((c + 1) * 32); // prefetch next chunk
#pragma unroll 8
        for (int k = 0; k < 32; k++) {
            float2 xv = *(const float2*)&xs[k * 132 + r0];
            float4 w0 = *(const float4*)&ws[k * 36 + cg * 8];
            float4 w1 = *(const float4*)&ws[k * 36 + cg * 8 + 4];
            acc[0][0] += xv.x * w0.x;
            acc[0][1] += xv.x * w0.y;
            acc[0][2] += xv.x * w0.z;
            acc[0][3] += xv.x * w0.w;
            acc[0][4] += xv.x * w1.x;
            acc[0][5] += xv.x * w1.y;
            acc[0][6] += xv.x * w1.z;
            acc[0][7] += xv.x * w1.w;
            acc[1][0] += xv.y * w0.x;
            acc[1][1] += xv.y * w0.y;
            acc[1][2] += xv.y * w0.z;
            acc[1][3] += xv.y * w0.w;
            acc[1][4] += xv.y * w1.x;
            acc[1][5] += xv.y * w1.y;
            acc[1][6] += xv.y * w1.z;
            acc[1][7] += xv.y * w1.w;
        }
    }

    // epilogue: h rows + es/ed (head == cg)
    float4 as0 = *(const float4*)&a_src[cg * 8];
    float4 as1 = *(const float4*)&a_src[cg * 8 + 4];
    float4 ad0 = *(const float4*)&a_dst[cg * 8];
    float4 ad1 = *(const float4*)&a_dst[cg * 8 + 4];
#pragma unroll
    for (int i = 0; i < 2; i++) {
        int r = row0 + r0 + i;
        if (r < N) {
            *(float4*)&h[(size_t)r * 32 + cg * 8] =
                make_float4(acc[i][0], acc[i][1], acc[i][2], acc[i][3]);
            *(float4*)&h[(size_t)r * 32 + cg * 8 + 4] =
                make_float4(acc[i][4], acc[i][5], acc[i][6], acc[i][7]);
            es[r * 4 + cg] = acc[i][0] * as0.x + acc[i][1] * as0.y +
                             acc[i][2] * as0.z + acc[i][3] * as0.w +
                             acc[i][4] * as1.x + acc[i][5] * as1.y +
                             acc[i][6] * as1.z + acc[i][7] * as1.w;
            ed[r * 4 + cg] = acc[i][0] * ad0.x + acc[i][1] * ad0.y +
                             acc[i][2] * ad0.z + acc[i][3] * ad0.w +
                             acc[i][4] * ad1.x + acc[i][5] * ad1.y +
                             acc[i][6] * ad1.z + acc[i][7] * ad1.w;
        }
    }
}

// Layer-1 aggregation (HC=32) with fused GEMM2 epilogue. One wave per dst,
// 4 dst/block. 8-deep gather batching. After the softmax reduce, lanes 0-31
// hold the relu(g1+bias) row; 32 readlane-broadcast FMAs against LDS W2
// produce h2[d][16] on lanes 0-15 plus es2/ed2 via 4-lane shfl reduce.
__global__ __launch_bounds__(256) void k_agg1(const int* __restrict__ row_ptr,
                                              const int* __restrict__ ssrc,
                                              const float* __restrict__ hsrc,
                                              const float* __restrict__ es,
                                              const float* __restrict__ ed,
                                              const float* __restrict__ bias,
                                              const float* __restrict__ W2,
                                              const float* __restrict__ a2s,
                                              const float* __restrict__ a2d,
                                              float* __restrict__ h2,
                                              float* __restrict__ es2,
                                              float* __restrict__ ed2, int N) {
    constexpr int U = 8;
    __shared__ float w2s[512];
    __shared__ float b1s[32];
    __shared__ float a2ss[16], a2ds[16];
    const int t = threadIdx.x;
    for (int i = t; i < 512; i += 256) w2s[i] = W2[i];
    if (t < 32) b1s[t] = bias[t];
    if (t < 16) { a2ss[t] = a2s[t]; a2ds[t] = a2d[t]; }
    __syncthreads(); // single barrier; safe to early-return after this

    const int lane = t & 63;
    const int d = blockIdx.x * 4 + (t >> 6);
    if (d >= N) return;
    const int c = lane & 31;
    const int e2 = lane >> 5;
    const int hh = c >> 3;
    const int start = row_ptr[d];
    const int deg = row_ptr[d + 1] - start;
    const float edh = ed[d * 4 + hh];
    const int j0 = (e2 < deg) ? e2 : 0;

    float l = 0.f, acc = 0.f;
    for (int jb = e2; jb < deg; jb += U * 2) {
        int sv[U];
        float wv[U];
#pragma unroll
        for (int u = 0; u < U; u++) {
            int jj = jb + u * 2;
            bool ok = jj < deg;
            wv[u] = ok ? 1.f : 0.f;
            sv[u] = ssrc[start + (ok ? jj : j0)];
        }
        float hv[U];
#pragma unroll
        for (int u = 0; u < U; u++) hv[u] = hsrc[(size_t)sv[u] * 32 + c];
        float pv[U];
#pragma unroll
        for (int u = 0; u < U; u++) {
            float ev = es[sv[u] * 4 + hh] + edh;
            ev = LRELU(ev);
            pv[u] = __expf(ev) * wv[u];
        }
#pragma unroll
        for (int u = 0; u < U; u++) {
            l += pv[u];
            acc += pv[u] * hv[u];
        }
    }
#pragma unroll
    for (int off = 32; off < 64; off <<= 1) {
        l += __shfl_xor(l, off);
        acc += __shfl_xor(acc, off);
    }
    // g1 value (relu + bias); valid on all 64 lanes (c duplicated hi/lo)
    float v = acc / (l + 1e-16f) + b1s[c];
    v = v > 0.f ? v : 0.f;

    // fused gemm2: h2[d][q] = sum_c g1[c] * W2[c][q]
    const int q = lane & 15;
    float h2q = 0.f;
#pragma unroll
    for (int cc = 0; cc < 32; cc++) {
        float gv = __shfl(v, cc); // broadcast channel cc from lane cc
        h2q += gv * w2s[cc * 16 + q];
    }
    float p1 = h2q * a2ss[q];
    float p2 = h2q * a2ds[q];
    p1 += __shfl_xor(p1, 1);
    p1 += __shfl_xor(p1, 2);
    p2 += __shfl_xor(p2, 1);
    p2 += __shfl_xor(p2, 2);
    if (lane < 16) {
        h2[(size_t)d * 16 + q] = h2q;
        if ((lane & 3) == 0) {
            es2[d * 4 + (lane >> 2)] = p1;
            ed2[d * 4 + (lane >> 2)] = p2;
        }
    }
}

// Layer-2 aggregation (HC=16), unchanged single-pass gather softmax.
template <int HC>
__global__ __launch_bounds__(256) void k_agg(const int* __restrict__ row_ptr,
                                             const int* __restrict__ ssrc,
                                             const float* __restrict__ hsrc,
                                             const float* __restrict__ es,
                                             const float* __restrict__ ed,
                                             const float* __restrict__ bias,
                                             float* __restrict__ out, int N) {
    constexpr int E2 = 64 / HC;
    constexpr int U = 8;
    const int lane = threadIdx.x & 63;
    const int d = blockIdx.x * 4 + (threadIdx.x >> 6);
    if (d >= N) return;
    const int c = lane & (HC - 1);
    const int e2 = lane / HC;
    const int hh = c / (HC / 4);
    const int start = row_ptr[d];
    const int deg = row_ptr[d + 1] - start;
    const float edh = ed[d * 4 + hh];
    const int j0 = (e2 < deg) ? e2 : 0;

    float l = 0.f, acc = 0.f;
    for (int jb = e2; jb < deg; jb += U * E2) {
        int sv[U];
        float wv[U];
#pragma unroll
        for (int u = 0; u < U; u++) {
            int jj = jb + u * E2;
            bool ok = jj < deg;
            wv[u] = ok ? 1.f : 0.f;
            sv[u] = ssrc[start + (ok ? jj : j0)];
        }
        float hv[U];
#pragma unroll
        for (int u = 0; u < U; u++) hv[u] = hsrc[(size_t)sv[u] * HC + c];
        float pv[U];
#pragma unroll
        for (int u = 0; u < U; u++) {
            float ev = es[sv[u] * 4 + hh] + edh;
            ev = LRELU(ev);
            pv[u] = __expf(ev) * wv[u];
        }
#pragma unroll
        for (int u = 0; u < U; u++) {
            l += pv[u];
            acc += pv[u] * hv[u];
        }
    }
#pragma unroll
    for (int off = HC; off < 64; off <<= 1) {
        l += __shfl_xor(l, off);
        acc += __shfl_xor(acc, off);
    }
    if (lane < HC) {
        float v = acc / (l + 1e-16f) + bias[c];
        out[(size_t)d * HC + c] = v > 0.f ? v : 0.f;
    }
}

// Pool (mean over sorted batch) + final linear. One block per graph.
__global__ __launch_bounds__(256) void k_final(const float* __restrict__ h3,
                                               const int* __restrict__ batch,
                                               const float* __restrict__ Wf,
                                               const float* __restrict__ bf,
                                               float* __restrict__ out, int N) {
    __shared__ float part[16][17];
    __shared__ float pooled[16];
    int g = blockIdx.x;
    int t = threadIdx.x;

    int lo = 0, b = N;
    while (lo < b) { int mid = (lo + b) >> 1; if (batch[mid] < g) lo = mid + 1; else b = mid; }
    int hi = lo; b = N;
    while (hi < b) { int mid = (hi + b) >> 1; if (batch[mid] < g + 1) hi = mid + 1; else b = mid; }

    int ch = t & 15, r = t >> 4;
    float acc = 0.f;
    for (int i = lo + r; i < hi; i += 16) acc += h3[(size_t)i * 16 + ch];
    part[r][ch] = acc;
    __syncthreads();
    if (t < 16) {
        float s = 0.f;
#pragma unroll
        for (int rr = 0; rr < 16; rr++) s += part[rr][t];
        float cnt = (float)(hi - lo);
        pooled[t] = s / fmaxf(cnt, 1.f);
    }
    __syncthreads();
    if (t < 10) {
        float v = bf[t];
#pragma unroll
        for (int cc = 0; cc < 16; cc++) v += pooled[cc] * Wf[cc * 10 + t];
        out[g * 10 + t] = v;
    }
}

extern "C" void kernel_launch(void* const* d_in, const int* in_sizes, int n_in,
                              void* d_out, int out_size, void* d_ws, size_t ws_size,
                              hipStream_t stream) {
    const float* x   = (const float*)d_in[0];
    const int*   ei  = (const int*)d_in[1];
    const int*   bat = (const int*)d_in[2];
    const float* W1  = (const float*)d_in[3];
    const float* as1 = (const float*)d_in[4];
    const float* ad1 = (const float*)d_in[5];
    const float* b1  = (const float*)d_in[6];
    const float* W2  = (const float*)d_in[7];
    const float* as2 = (const float*)d_in[8];
    const float* ad2 = (const float*)d_in[9];
    const float* b2  = (const float*)d_in[10];
    const float* Wf  = (const float*)d_in[11];
    const float* bf  = (const float*)d_in[12];
    float* outp = (float*)d_out;

    const int N = in_sizes[2];
    const int E0 = in_sizes[1] / 2;
    const int Etot = E0 + N;
    const int nr = (N + 255) >> 8;    // 256-node dst ranges (<=1024)
    const int cap = Etot / nr + 2048; // per-range staging cap (~20 sigma)

    char* w = (char*)d_ws;
    auto alloc = [&](size_t bytes) -> char* {
        char* p = w;
        w += (bytes + 255) & ~(size_t)255;
        return p;
    };
    float* h1  = (float*)alloc((size_t)N * 32 * 4);
    float* es1 = (float*)alloc((size_t)N * 4 * 4);
    float* ed1 = (float*)alloc((size_t)N * 4 * 4);
    float* h2  = (float*)alloc((size_t)N * 16 * 4);
    float* es2 = (float*)alloc((size_t)N * 4 * 4);
    float* ed2 = (float*)alloc((size_t)N * 4 * 4);
    int* rcnt    = (int*)alloc(4096);
    int* row_ptr = (int*)alloc((size_t)(N + 1) * 4);
    int* ssrc    = (int*)alloc((size_t)Etot * 4);
    int2* stg    = (int2*)alloc((size_t)nr * cap * 8);
    float* h3 = h1; // h1 dead after agg1; reuse for layer-2 output

    const int nb1 = (N + 127) / 128;

    hipMemsetAsync(rcnt, 0, 4096, stream);
    k_bin<<<(Etot + 8191) / 8192, 256, 0, stream>>>(ei, stg, rcnt, E0, Etot, nr, cap);
    k_sort<<<nr, 512, 0, stream>>>(stg, rcnt, row_ptr, ssrc, N, Etot, nr, cap);
    k_gemm1<<<nb1, 256, 0, stream>>>(x, W1, as1, ad1, h1, es1, ed1, N);
    k_agg1<<<(N + 3) / 4, 256, 0, stream>>>(row_ptr, ssrc, h1, es1, ed1, b1,
                                            W2, as2, ad2, h2, es2, ed2, N);
    k_agg<16><<<(N + 3) / 4, 256, 0, stream>>>(row_ptr, ssrc, h2, es2, ed2, b2, h3, N);
    k_final<<<64, 256, 0, stream>>>(h3, bat, Wf, bf, outp, N);
}